// Round 1
// baseline (533.876 us; speedup 1.0000x reference)
//
#include <hip/hip_runtime.h>
#include <stdint.h>

#define NB 512
#define SL 1024
#define NT 64

__device__ __forceinline__ float wave_max6(float v) {
    #pragma unroll
    for (int off = 32; off >= 1; off >>= 1)
        v = fmaxf(v, __shfl_xor(v, off, 64));
    return v;
}
__device__ __forceinline__ float wave_sum_f(float v) {
    #pragma unroll
    for (int off = 32; off >= 1; off >>= 1)
        v += __shfl_xor(v, off, 64);
    return v;
}

// ---------------- Kernel A: gold-path score + lengths ----------------
__global__ void __launch_bounds__(256) crf_score_kernel(
    const int* __restrict__ tags, const void* __restrict__ mask,
    const float* __restrict__ emit, const float* __restrict__ trans,
    float* __restrict__ ts, int* __restrict__ lens)
{
    const int b = blockIdx.x;
    const int tid = threadIdx.x;
    const unsigned char* mb = (const unsigned char*)mask;
    // dtype sniff: int32 bool -> bytes 1..3 of first element are zero
    const bool mask_is_i32 = ((mb[1] | mb[2] | mb[3]) == 0);

    const int* trow = tags + b * SL;
    const float* erow = emit + (size_t)b * SL * NT;

    float acc = 0.f;
    int cnt = 0;
    for (int i = tid; i < SL; i += 256) {
        bool mk = mask_is_i32 ? (((const int*)mask)[(size_t)b * SL + i] != 0)
                              : (mb[(size_t)b * SL + i] != 0);
        if (mk) {
            int tg = trow[i];
            float v = erow[(size_t)i * NT + tg];
            if (i > 0) v += trans[trow[i - 1] * NT + tg];
            acc += v;
            cnt++;
        }
    }
    #pragma unroll
    for (int off = 32; off >= 1; off >>= 1) {
        acc += __shfl_xor(acc, off, 64);
        cnt += __shfl_xor(cnt, off, 64);
    }
    __shared__ float sa[4];
    __shared__ int   sc[4];
    int w = tid >> 6;
    if ((tid & 63) == 0) { sa[w] = acc; sc[w] = cnt; }
    __syncthreads();
    if (tid == 0) {
        ts[b]   = (sa[0] + sa[1]) + (sa[2] + sa[3]);
        lens[b] = (sc[0] + sc[1]) + (sc[2] + sc[3]);
    }
}

// ---------------- Kernel B: forward scan (one wave per batch row) ----------------
__global__ void __launch_bounds__(64) crf_scan_kernel(
    const float* __restrict__ emit, const float* __restrict__ trans,
    const float* __restrict__ ts, const int* __restrict__ lens,
    float* __restrict__ out)
{
    const int b = blockIdx.x;
    const int lane = threadIdx.x;
    const float* erow = emit + (size_t)b * SL * NT;

    // Ecol[p] = exp(trans[p][lane]) : column of exp(transition) for this lane's tag
    float Ecol[NT];
    #pragma unroll
    for (int p = 0; p < NT; ++p)
        Ecol[p] = __expf(trans[p * NT + lane]);

    __shared__ __align__(16) float vbuf[2][NT];

    // init: v = exp(d0 - m0), logacc = m0
    float d0 = erow[lane];
    float m0 = wave_max6(d0);
    float v = __expf(d0 - m0);
    float logacc = m0;
    const int len = lens[b];

    int buf = 0;

    // one scan step: v'[t] = (sum_p v[p]*Ecol[p][t]) * exp(em[t])
#define STEP(EM)                                                   \
    {                                                              \
        vbuf[buf][lane] = v;                                       \
        __syncthreads();                                           \
        float s0 = 0.f, s1 = 0.f, s2 = 0.f, s3 = 0.f;              \
        const float4* vb = (const float4*)(&vbuf[buf][0]);         \
        _Pragma("unroll")                                          \
        for (int k = 0; k < 16; ++k) {                             \
            float4 q = vb[k];                                      \
            s0 = fmaf(q.x, Ecol[4 * k + 0], s0);                   \
            s1 = fmaf(q.y, Ecol[4 * k + 1], s1);                   \
            s2 = fmaf(q.z, Ecol[4 * k + 2], s2);                   \
            s3 = fmaf(q.w, Ecol[4 * k + 3], s3);                   \
        }                                                          \
        v = ((s0 + s1) + (s2 + s3)) * __expf(EM);                  \
        buf ^= 1;                                                  \
    }

    const int nstep = len - 1;      // steps i = 1 .. len-1
    const int ngrp  = nstep >> 2;   // groups of 4 steps
    int i = 1;

    float4 emq;
    if (ngrp > 0) {  // prefetch first group's emit values
        emq.x = erow[(i + 0) * NT + lane];
        emq.y = erow[(i + 1) * NT + lane];
        emq.z = erow[(i + 2) * NT + lane];
        emq.w = erow[(i + 3) * NT + lane];
    }
    for (int g = 0; g < ngrp; ++g) {
        float4 cur = emq;
        int ip = i + 4;
        if (g + 1 < ngrp) {  // prefetch next group (hides L3/HBM latency)
            emq.x = erow[(ip + 0) * NT + lane];
            emq.y = erow[(ip + 1) * NT + lane];
            emq.z = erow[(ip + 2) * NT + lane];
            emq.w = erow[(ip + 3) * NT + lane];
        }
        STEP(cur.x)
        STEP(cur.y)
        STEP(cur.z)
        STEP(cur.w)
        // cheap renorm: exact power-of-2 rescale, uniform scale via sampled max
        {
            float m = v;
            m = fmaxf(m, __shfl_xor(m, 32, 64));
            m = fmaxf(m, __shfl_xor(m, 16, 64));
            m = __int_as_float(__builtin_amdgcn_readfirstlane(__float_as_int(m)));
            int ex = (__float_as_int(m) >> 23) & 0xff;       // biased exponent
            float scale = __int_as_float((254 - ex) << 23);  // 2^(127-ex), exact
            v *= scale;
            logacc += (float)(ex - 127) * 0.69314718055994530942f;
        }
        i += 4;
    }
    // remainder steps (<=3)
    for (; i < len; ++i) {
        float em = erow[i * NT + lane];
        STEP(em)
    }
#undef STEP

    float sum = wave_sum_f(v);
    float log_z = logacc + __logf(sum);
    if (lane == 0) out[b] = -(ts[b] - log_z);
}

extern "C" void kernel_launch(void* const* d_in, const int* in_sizes, int n_in,
                              void* d_out, int out_size, void* d_ws, size_t ws_size,
                              hipStream_t stream) {
    (void)in_sizes; (void)n_in; (void)out_size; (void)ws_size;
    const int*   tags  = (const int*)d_in[0];
    const void*  mask  = d_in[1];
    const float* emit  = (const float*)d_in[2];
    const float* trans = (const float*)d_in[3];
    float* out = (float*)d_out;

    float* ts   = (float*)d_ws;
    int*   lens = (int*)((char*)d_ws + NB * sizeof(float));

    crf_score_kernel<<<dim3(NB), dim3(256), 0, stream>>>(tags, mask, emit, trans, ts, lens);
    crf_scan_kernel<<<dim3(NB), dim3(64), 0, stream>>>(emit, trans, ts, lens, out);
}

// Round 2
// 456.370 us; speedup vs baseline: 1.1698x; 1.1698x over previous
//
#include <hip/hip_runtime.h>
#include <stdint.h>

#define NB 512
#define SL 1024
#define NT 64

typedef float v2f __attribute__((ext_vector_type(2)));
typedef float v4f __attribute__((ext_vector_type(4)));

__device__ __forceinline__ float wave_max6(float v) {
    #pragma unroll
    for (int off = 32; off >= 1; off >>= 1)
        v = fmaxf(v, __shfl_xor(v, off, 64));
    return v;
}
__device__ __forceinline__ float wave_sum_f(float v) {
    #pragma unroll
    for (int off = 32; off >= 1; off >>= 1)
        v += __shfl_xor(v, off, 64);
    return v;
}

// One block (= one wave) per batch row: computes gold score, then the forward
// scan in scaled-exp domain, then writes the loss.
__global__ void __launch_bounds__(64) crf_fused_kernel(
    const int* __restrict__ tags, const void* __restrict__ mask,
    const float* __restrict__ emit, const float* __restrict__ trans,
    float* __restrict__ out)
{
    const int b = blockIdx.x;
    const int lane = threadIdx.x;
    const float* erow = emit + (size_t)b * SL * NT;
    const int* trow = tags + b * SL;

    // ---------- phase 0: gold-path score + length (latency-bound gathers,
    // runs once; waves are mostly idle anyway) ----------
    const unsigned char* mb = (const unsigned char*)mask;
    const bool mask_is_i32 = ((mb[1] | mb[2] | mb[3]) == 0);  // dtype sniff

    float acc = 0.f; int cnt = 0;
    #pragma unroll
    for (int j = 0; j < 16; ++j) {
        const int i = lane + 64 * j;
        const int mk = mask_is_i32 ? (((const int*)mask)[(size_t)b * SL + i] != 0)
                                   : (mb[(size_t)b * SL + i] != 0);
        if (mk) {
            const int tg = trow[i];
            float val = erow[(size_t)i * NT + tg];
            if (i > 0) val += trans[trow[i - 1] * NT + tg];
            acc += val; cnt += 1;
        }
    }
    #pragma unroll
    for (int off = 32; off >= 1; off >>= 1) {
        acc += __shfl_xor(acc, off, 64);
        cnt += __shfl_xor(cnt, off, 64);
    }
    const float ts = acc;
    const int len = cnt;

    // ---------- phase 1: forward scan ----------
    // E2[k] = {exp(trans[2k][lane]), exp(trans[2k+1][lane])} : this lane's
    // column of exp(transition), packed for v_pk_fma_f32.
    v2f E2[NT / 2];
    #pragma unroll
    for (int k = 0; k < NT / 2; ++k) {
        E2[k].x = __expf(trans[(2 * k + 0) * NT + lane]);
        E2[k].y = __expf(trans[(2 * k + 1) * NT + lane]);
    }

    __shared__ __align__(16) float vbuf[NT];

    float d0 = erow[lane];
    float m0 = wave_max6(d0);
    float v = __expf(d0 - m0);
    float logacc = m0;

    // One scan step: v'[t] = (sum_p v[p]*Ecol[p][t]) * EX  where EX=exp(emit).
    // Single wave: DS unit processes this wave's LDS ops in order, so no
    // s_barrier is needed — wave_barrier() only pins compiler ordering.
#define STEP(EX)                                                           \
    {                                                                      \
        vbuf[lane] = v;                                                    \
        __builtin_amdgcn_wave_barrier();                                   \
        v2f a0 = {0.f, 0.f}, a1 = {0.f, 0.f}, a2 = {0.f, 0.f},             \
            a3 = {0.f, 0.f};                                               \
        const v4f* vb = (const v4f*)vbuf;                                  \
        _Pragma("unroll")                                                  \
        for (int k = 0; k < 16; ++k) {                                     \
            v4f q = vb[k];                                                 \
            v2f qlo; qlo.x = q.x; qlo.y = q.y;                             \
            v2f qhi; qhi.x = q.z; qhi.y = q.w;                             \
            if (k & 1) {                                                   \
                asm("v_pk_fma_f32 %0, %1, %2, %0"                          \
                    : "+v"(a2) : "v"(qlo), "v"(E2[2 * k]));                \
                asm("v_pk_fma_f32 %0, %1, %2, %0"                          \
                    : "+v"(a3) : "v"(qhi), "v"(E2[2 * k + 1]));            \
            } else {                                                       \
                asm("v_pk_fma_f32 %0, %1, %2, %0"                          \
                    : "+v"(a0) : "v"(qlo), "v"(E2[2 * k]));                \
                asm("v_pk_fma_f32 %0, %1, %2, %0"                          \
                    : "+v"(a1) : "v"(qhi), "v"(E2[2 * k + 1]));            \
            }                                                              \
        }                                                                  \
        v2f h = (a0 + a2) + (a1 + a3);                                     \
        v = (h.x + h.y) * (EX);                                            \
    }

    const int nstep = len - 1;     // steps i = 1 .. len-1
    const int ngrp = nstep >> 2;   // groups of 4
    int i = 1;

    v4f emq;
    if (ngrp > 0) {
        emq.x = erow[(i + 0) * NT + lane];
        emq.y = erow[(i + 1) * NT + lane];
        emq.z = erow[(i + 2) * NT + lane];
        emq.w = erow[(i + 3) * NT + lane];
    }
    for (int g = 0; g < ngrp; ++g) {
        // exps are independent of the chain: issue them first
        float ex0 = __expf(emq.x), ex1 = __expf(emq.y);
        float ex2 = __expf(emq.z), ex3 = __expf(emq.w);
        const int ip = i + 4;
        if (g + 1 < ngrp) {  // prefetch next group's emissions
            emq.x = erow[(ip + 0) * NT + lane];
            emq.y = erow[(ip + 1) * NT + lane];
            emq.z = erow[(ip + 2) * NT + lane];
            emq.w = erow[(ip + 3) * NT + lane];
        }
        STEP(ex0)
        STEP(ex1)
        STEP(ex2)
        STEP(ex3)
        // renorm: exact power-of-2 rescale. Any lane's exponent works as a
        // wave-uniform scale: within-step spread across lanes <= e^16, and
        // 4-step growth <= e^44, so worst case stays far inside fp32 range.
        {
            uint32_t sb = __builtin_amdgcn_readfirstlane(__float_as_uint(v));
            int ex = (int)((sb >> 23) & 0xffu);
            v *= __uint_as_float((uint32_t)(254 - ex) << 23);  // 2^(127-ex)
            logacc += (float)(ex - 127) * 0.69314718055994530942f;
        }
        i += 4;
    }
    for (; i < len; ++i) {  // remainder (<=3 steps)
        float e = __expf(erow[i * NT + lane]);
        STEP(e)
    }
#undef STEP

    float sum = wave_sum_f(v);
    float log_z = logacc + __logf(sum);
    if (lane == 0) out[b] = -(ts - log_z);
}

extern "C" void kernel_launch(void* const* d_in, const int* in_sizes, int n_in,
                              void* d_out, int out_size, void* d_ws, size_t ws_size,
                              hipStream_t stream) {
    (void)in_sizes; (void)n_in; (void)out_size; (void)d_ws; (void)ws_size;
    const int*   tags  = (const int*)d_in[0];
    const void*  mask  = d_in[1];
    const float* emit  = (const float*)d_in[2];
    const float* trans = (const float*)d_in[3];
    float* out = (float*)d_out;

    crf_fused_kernel<<<dim3(NB), dim3(64), 0, stream>>>(tags, mask, emit, trans, out);
}

// Round 3
// 385.849 us; speedup vs baseline: 1.3836x; 1.1828x over previous
//
#include <hip/hip_runtime.h>
#include <stdint.h>

#define NB 512
#define SL 1024
#define NT 64

typedef float v4f __attribute__((ext_vector_type(4)));

__device__ __forceinline__ float wave_max6(float v) {
    #pragma unroll
    for (int off = 32; off >= 1; off >>= 1)
        v = fmaxf(v, __shfl_xor(v, off, 64));
    return v;
}
__device__ __forceinline__ float wave_sum_f(float v) {
    #pragma unroll
    for (int off = 32; off >= 1; off >>= 1)
        v += __shfl_xor(v, off, 64);
    return v;
}

// RNE round fp32 -> bf16 (as uint16 in low bits)
__device__ __forceinline__ uint32_t bf16_rne(float x) {
    uint32_t u = __float_as_uint(x);
    return (u + 0x7fffu + ((u >> 16) & 1u)) >> 16;
}

// packed bf16 dot2 accumulate: acc += a.lo*b.lo + a.hi*b.hi
__device__ __forceinline__ void dot2bf(float& acc, uint32_t a, uint32_t b) {
    asm("v_dot2_f32_bf16 %0, %1, %2, %0" : "+v"(acc) : "v"(a), "v"(b));
}

// One block (= one wave) per batch row: gold score + forward scan in
// scaled-exp domain with bf16 broadcast of the state vector.
__global__ void __launch_bounds__(64) crf_fused_kernel(
    const int* __restrict__ tags, const void* __restrict__ mask,
    const float* __restrict__ emit, const float* __restrict__ trans,
    float* __restrict__ out)
{
    const int b = blockIdx.x;
    const int lane = threadIdx.x;
    const float* erow = emit + (size_t)b * SL * NT;
    const int* trow = tags + b * SL;

    // ---------- phase 0: gold-path score + length ----------
    const unsigned char* mb = (const unsigned char*)mask;
    const bool mask_is_i32 = ((mb[1] | mb[2] | mb[3]) == 0);  // dtype sniff

    float acc = 0.f; int cnt = 0;
    #pragma unroll
    for (int j = 0; j < 16; ++j) {
        const int i = lane + 64 * j;
        const int mk = mask_is_i32 ? (((const int*)mask)[(size_t)b * SL + i] != 0)
                                   : (mb[(size_t)b * SL + i] != 0);
        if (mk) {
            const int tg = trow[i];
            float val = erow[(size_t)i * NT + tg];
            if (i > 0) val += trans[trow[i - 1] * NT + tg];
            acc += val; cnt += 1;
        }
    }
    #pragma unroll
    for (int off = 32; off >= 1; off >>= 1) {
        acc += __shfl_xor(acc, off, 64);
        cnt += __shfl_xor(cnt, off, 64);
    }
    const float ts = acc;
    const int len = cnt;

    // ---------- phase 1: forward scan ----------
    // Epk[m] = packed bf16 pair { exp(trans[2m][lane]), exp(trans[2m+1][lane]) }
    // i.e. this lane's column of exp(transition), pair-packed to match the
    // dword layout of the bf16 state buffer.
    uint32_t Epk[NT / 2];
    #pragma unroll
    for (int m = 0; m < NT / 2; ++m) {
        uint32_t lo = bf16_rne(__expf(trans[(2 * m + 0) * NT + lane]));
        uint32_t hi = bf16_rne(__expf(trans[(2 * m + 1) * NT + lane]));
        Epk[m] = lo | (hi << 16);
    }

    __shared__ __align__(16) uint16_t vbuf16[NT];  // state broadcast, bf16

    float d0 = erow[lane];
    float m0 = wave_max6(d0);
    float v = __expf(d0 - m0);
    float logacc = m0;

    // One scan step: v'[t] = (sum_p v[p]*E[p][t]) * EX,  EX = exp(emit).
    // Single wave: the DS pipe is in-order for one wave, so the b16 write is
    // seen by the following b128 reads without any s_barrier.
#define STEP(EX)                                                           \
    {                                                                      \
        vbuf16[lane] = (uint16_t)bf16_rne(v);                              \
        __builtin_amdgcn_wave_barrier();                                   \
        float a0 = 0.f, a1 = 0.f, a2 = 0.f, a3 = 0.f;                      \
        float a4 = 0.f, a5 = 0.f, a6 = 0.f, a7 = 0.f;                      \
        const uint4* vb = (const uint4*)vbuf16;                            \
        _Pragma("unroll")                                                  \
        for (int r = 0; r < 8; r += 2) {                                   \
            uint4 q0 = vb[r];                                              \
            uint4 q1 = vb[r + 1];                                          \
            dot2bf(a0, q0.x, Epk[4 * r + 0]);                              \
            dot2bf(a1, q0.y, Epk[4 * r + 1]);                              \
            dot2bf(a2, q0.z, Epk[4 * r + 2]);                              \
            dot2bf(a3, q0.w, Epk[4 * r + 3]);                              \
            dot2bf(a4, q1.x, Epk[4 * r + 4]);                              \
            dot2bf(a5, q1.y, Epk[4 * r + 5]);                              \
            dot2bf(a6, q1.z, Epk[4 * r + 6]);                              \
            dot2bf(a7, q1.w, Epk[4 * r + 7]);                              \
        }                                                                  \
        float h = ((a0 + a1) + (a2 + a3)) + ((a4 + a5) + (a6 + a7));       \
        v = h * (EX);                                                      \
    }

    const int nstep = len - 1;     // steps i = 1 .. len-1
    const int ngrp = nstep >> 2;   // groups of 4
    int i = 1;

    v4f emq;
    if (ngrp > 0) {
        emq.x = erow[(i + 0) * NT + lane];
        emq.y = erow[(i + 1) * NT + lane];
        emq.z = erow[(i + 2) * NT + lane];
        emq.w = erow[(i + 3) * NT + lane];
    }
    for (int g = 0; g < ngrp; ++g) {
        // emission exps are independent of the chain: issue first
        float ex0 = __expf(emq.x), ex1 = __expf(emq.y);
        float ex2 = __expf(emq.z), ex3 = __expf(emq.w);
        const int ip = i + 4;
        if (g + 1 < ngrp) {  // prefetch next group's emissions
            emq.x = erow[(ip + 0) * NT + lane];
            emq.y = erow[(ip + 1) * NT + lane];
            emq.z = erow[(ip + 2) * NT + lane];
            emq.w = erow[(ip + 3) * NT + lane];
        }
        STEP(ex0)
        STEP(ex1)
        STEP(ex2)
        STEP(ex3)
        // renorm: exact power-of-2 rescale; any lane's exponent is a safe
        // wave-uniform scale (inter-lane spread is bounded, see notes).
        {
            uint32_t sb = __builtin_amdgcn_readfirstlane(__float_as_uint(v));
            int ex = (int)((sb >> 23) & 0xffu);
            v *= __uint_as_float((uint32_t)(254 - ex) << 23);  // 2^(127-ex)
            logacc += (float)(ex - 127) * 0.69314718055994530942f;
        }
        i += 4;
    }
    for (; i < len; ++i) {  // remainder (<=3 steps)
        float e = __expf(erow[i * NT + lane]);
        STEP(e)
    }
#undef STEP

    float sum = wave_sum_f(v);
    float log_z = logacc + __logf(sum);
    if (lane == 0) out[b] = -(ts - log_z);
}

extern "C" void kernel_launch(void* const* d_in, const int* in_sizes, int n_in,
                              void* d_out, int out_size, void* d_ws, size_t ws_size,
                              hipStream_t stream) {
    (void)in_sizes; (void)n_in; (void)out_size; (void)d_ws; (void)ws_size;
    const int*   tags  = (const int*)d_in[0];
    const void*  mask  = d_in[1];
    const float* emit  = (const float*)d_in[2];
    const float* trans = (const float*)d_in[3];
    float* out = (float*)d_out;

    crf_fused_kernel<<<dim3(NB), dim3(64), 0, stream>>>(tags, mask, emit, trans, out);
}